// Round 5
// baseline (123.659 us; speedup 1.0000x reference)
//
#include <hip/hip_runtime.h>

#define NSPEC  3
#define EMBEDD 16
#define KMAX   32
#define RCUT   5.0f
#define PADR   36   // padded row stride (floats) for phiT

// triu_indices(8) row-major
__constant__ int TUN[36] = {0,0,0,0,0,0,0,0, 1,1,1,1,1,1,1, 2,2,2,2,2,2, 3,3,3,3,3, 4,4,4,4, 5,5,5, 6,6, 7};
__constant__ int TUM[36] = {0,1,2,3,4,5,6,7, 1,2,3,4,5,6,7, 2,3,4,5,6,7, 3,4,5,6,7, 4,5,6,7, 5,6,7, 6,7, 7};

// ws layout (from magpot_setup):
//   [0..79]    wstruct[16+t]/sscale[t]
//   [80..330]  wmag[16+t]/mscale[t]          (dmi slots 83..146/163..226 unused by main)
//   [331]      bstruct+bmag - sum_t w*shift/scale
//   [332..347] wstruct[l]+wmag[l]
//   [400..463] cw1T[m*8+n] = wmag[16+83+n*8+m]/mscale[83+n*8+m]    (transposed DMI weights)
//   [464..527] cw2T[m*8+n] = wmag[16+163+n*8+m]/mscale[163+n*8+m]  (u*dmi weights)

// ---- DPP helpers (VALU-only cross-lane; ds_swizzle only for xor16) ----
template<int CTRL, int RMASK, bool BC>
__device__ __forceinline__ float dpp_mov0(float x) {
    return __int_as_float(__builtin_amdgcn_update_dpp(
        0, __float_as_int(x), CTRL, RMASK, 0xF, BC));
}
__device__ __forceinline__ float prefix32(float x) {
    x += dpp_mov0<0x111, 0xF, true >(x);   // row_shr:1
    x += dpp_mov0<0x112, 0xF, true >(x);   // row_shr:2
    x += dpp_mov0<0x114, 0xF, true >(x);   // row_shr:4
    x += dpp_mov0<0x118, 0xF, true >(x);   // row_shr:8
    x += dpp_mov0<0x142, 0xA, false>(x);   // row_bcast15 -> rows 1,3
    return x;
}
__device__ __forceinline__ float swz_xor16(float x) {
    return __int_as_float(__builtin_amdgcn_ds_swizzle(__float_as_int(x), 0x401F));
}
__device__ __forceinline__ float red_k4(float x) {   // reduce lane bits 3,4
    x += dpp_mov0<0x128, 0xF, true>(x);    // row_ror:8 == xor 8
    x += swz_xor16(x);                     // xor 16 (within each 32-half)
    return x;
}
__device__ __forceinline__ float red32(float x) {    // full 32-half sum
    x += dpp_mov0<0x121, 0xF, true>(x);
    x += dpp_mov0<0x122, 0xF, true>(x);
    x += dpp_mov0<0x124, 0xF, true>(x);
    x += dpp_mov0<0x128, 0xF, true>(x);
    x += swz_xor16(x);
    return x;
}

// Wave-local LDS fence (all AtomLds traffic is intra-wave; no __syncthreads needed)
__device__ __forceinline__ void lds_fence() {
    asm volatile("s_waitcnt lgkmcnt(0)" ::: "memory");
}

struct __align__(16) AtomLds {
    float phiT[8 * PADR];                     // 288: phiT[n*PADR + a]
    float rhx[KMAX], rhy[KMAX], rhz[KMAX];    // edge data (phase 1 -> 2 only)
    float mdx[KMAX], mdy[KMAX], mdz[KMAX];
    float uj[KMAX];
    float P4[8*4];    // P rows padded to float4
    float Q8[8*8];    // Q rows padded to 8 (q0..q5 = xx,xy,xz,yy,yz,zz)
    float M4[8*4];
    float mQ4[8*4];
    float wv4[8*4];   // m_i x M[m], padded
};  // 672 floats = 2688 B

__global__ __launch_bounds__(256)
void magpot_setup(const float* __restrict__ sshift, const float* __restrict__ sscale,
                  const float* __restrict__ mshift, const float* __restrict__ mscale,
                  const float* __restrict__ wstruct, const float* __restrict__ bstruct,
                  const float* __restrict__ wmag, const float* __restrict__ bmag,
                  float* __restrict__ ws)
{
    __shared__ float red[4];
    const int t = threadIdx.x;
    float c = 0.0f;
    for (int idx = t; idx < 80; idx += 256) {
        const float w = wstruct[16 + idx] / sscale[idx];
        ws[idx] = w;
        c += w * sshift[idx];
    }
    for (int idx = t; idx < 251; idx += 256) {
        const float w = wmag[16 + idx] / mscale[idx];
        ws[80 + idx] = w;
        c += w * mshift[idx];
    }
    if (t < EMBEDD) ws[332 + t] = wstruct[t] + wmag[t];
    if (t < 64) {   // transposed DMI weight tables (idx = n*8+m)
        const int n = t >> 3, m = t & 7;
        ws[400 + m*8 + n] = wmag[16 + 83 + t]  / mscale[83 + t];
        ws[464 + m*8 + n] = wmag[16 + 163 + t] / mscale[163 + t];
    }
    #pragma unroll
    for (int d = 1; d <= 32; d <<= 1) c += __shfl_xor(c, d, 64);
    if ((t & 63) == 0) red[t >> 6] = c;
    __syncthreads();
    if (t == 0) ws[331] = bstruct[0] + bmag[0] - (red[0] + red[1] + red[2] + red[3]);
}

__global__ __launch_bounds__(256)
void magpot_main(const float* __restrict__ pos,
                 const int*   __restrict__ species,
                 const float* __restrict__ mag,
                 const int*   __restrict__ eidx,
                 const float* __restrict__ shifts,
                 const float* __restrict__ rb,
                 const float* __restrict__ semb,
                 const float* __restrict__ aes,
                 const float* __restrict__ ws,
                 float* __restrict__ out,
                 int N, int E, int K)
{
    __shared__ AtomLds lds[8];

    const int lane64 = threadIdx.x & 63;
    const int wv     = threadIdx.x >> 6;
    const int h      = lane64 >> 5;        // half (atom within wave)
    const int s      = lane64 & 31;
    const int ea     = 31 - s;             // edge index (reversed: suffix -> DPP prefix)
    const int i      = blockIdx.x * 8 + wv * 2 + h;
    const bool valid = (i < N);
    const int isafe  = valid ? i : 0;
    AtomLds& L = lds[wv * 2 + h];

    const float* wm = ws + 80;

    // ---- atom-level quantities (broadcast within each half) ----
    const float pix = pos[3*isafe+0], piy = pos[3*isafe+1], piz = pos[3*isafe+2];
    const int   spi = species[isafe];
    const float mgx = mag[3*isafe+0], mgy = mag[3*isafe+1], mgz = mag[3*isafe+2];
    const float u_i = mgx*mgx + mgy*mgy + mgz*mgz;
    const float mn_i = sqrtf(u_i);
    const float mi_inv = (mn_i > 1e-8f) ? (1.0f / mn_i) : 0.0f;
    const float mix = mgx*mi_inv, miy = mgy*mi_inv, miz = mgz*mi_inv;

    // ---- phase 1: per-edge (this lane owns edge ea of atom i) ----
    float phi[8];
    float rx = 0.0f, ry = 0.0f, rz = 0.0f;
    #pragma unroll
    for (int n = 0; n < 8; ++n) phi[n] = 0.0f;

    if (ea < K) {
        const int e = isafe * K + ea;
        const int j = eidx[E + e];
        rx = pos[3*j+0] - pix + shifts[3*e+0];
        ry = pos[3*j+1] - piy + shifts[3*e+1];
        rz = pos[3*j+2] - piz + shifts[3*e+2];
        const float dist = sqrtf(rx*rx + ry*ry + rz*rz);
        // cos(pi*d/5) = cos(2*pi*(d/10)); v_cos_f32 takes revolutions
        const float fc = (dist < RCUT)
            ? (0.5f * __builtin_amdgcn_cosf(dist * 0.1f) + 0.5f)
            : 0.0f;
        const float xr = dist * (1.0f/RCUT);
        const float x  = 2.0f * xr * xr - 1.0f;
        float f[8];
        {
            float Tm2 = 1.0f, Tm1 = x;
            f[0] = 0.5f * (Tm2 + 1.0f) * fc;
            f[1] = 0.5f * (Tm1 + 1.0f) * fc;
            #pragma unroll
            for (int k = 2; k < 8; ++k) {
                const float T = 2.0f * x * Tm1 - Tm2;
                Tm2 = Tm1; Tm1 = T;
                f[k] = 0.5f * (T + 1.0f) * fc;
            }
        }
        const int spj = species[j];
        const float4* rb4 = (const float4*)(rb + (spi * NSPEC + spj) * 64);
        #pragma unroll
        for (int n = 0; n < 8; ++n) {
            const float4 r0 = rb4[n*2+0];
            const float4 r1 = rb4[n*2+1];
            const float ph = r0.x*f[0] + r0.y*f[1] + r0.z*f[2] + r0.w*f[3]
                           + r1.x*f[4] + r1.y*f[5] + r1.z*f[6] + r1.w*f[7];
            phi[n] = ph;
            L.phiT[n*PADR + ea] = ph;
        }
        const float dinv = 1.0f / fmaxf(dist, 1e-8f);
        L.rhx[ea] = rx * dinv;
        L.rhy[ea] = ry * dinv;
        L.rhz[ea] = rz * dinv;
        const float mjx = mag[3*j+0], mjy = mag[3*j+1], mjz = mag[3*j+2];
        const float uj = mjx*mjx + mjy*mjy + mjz*mjz;
        const float mnj = sqrtf(uj);
        const float mjinv = (mnj > 1e-8f) ? (1.0f / mnj) : 0.0f;
        L.mdx[ea] = mjx * mjinv;
        L.mdy[ea] = mjy * mjinv;
        L.mdz[ea] = mjz * mjinv;
        L.uj[ea] = uj;
    } else {
        #pragma unroll
        for (int n = 0; n < 8; ++n) L.phiT[n*PADR + ea] = 0.0f;
        L.rhx[ea] = 0.0f; L.rhy[ea] = 0.0f; L.rhz[ea] = 0.0f;
        L.mdx[ea] = 0.0f; L.mdy[ea] = 0.0f; L.mdz[ea] = 0.0f;
        L.uj[ea] = 0.0f;
    }
    lds_fence();   // phase-1 stores -> phase-2 reads (intra-wave)

    float p = 0.0f;   // fused weighted-descriptor accumulator

    // ---- phase 2: segment sums + full epilogue in k4==0 lanes ----
    {
        const int k4 = s >> 3;
        const int n  = s & 7;
        const float4* phR = (const float4*)&L.phiT[n*PADR + k4*8];
        const float4* hxR = (const float4*)&L.rhx[k4*8];
        const float4* hyR = (const float4*)&L.rhy[k4*8];
        const float4* hzR = (const float4*)&L.rhz[k4*8];
        const float4* dxR = (const float4*)&L.mdx[k4*8];
        const float4* dyR = (const float4*)&L.mdy[k4*8];
        const float4* dzR = (const float4*)&L.mdz[k4*8];
        const float4* ujR = (const float4*)&L.uj[k4*8];

        float a_dr = 0.0f;
        float aP0 = 0.0f, aP1 = 0.0f, aP2 = 0.0f;
        float aQ0 = 0.0f, aQ1 = 0.0f, aQ2 = 0.0f, aQ3 = 0.0f, aQ4 = 0.0f, aQ5 = 0.0f;
        float aM0 = 0.0f, aM1 = 0.0f, aM2 = 0.0f;
        float a_nb = 0.0f;
        float aW0 = 0.0f, aW1 = 0.0f, aW2 = 0.0f;

        auto acc = [&](float ph, float hx, float hy, float hz,
                       float dx, float dy, float dz, float uj) {
            a_dr += ph;
            aP0 += ph*hx; aP1 += ph*hy; aP2 += ph*hz;
            aQ0 += ph*(hx*hx - (1.0f/3.0f));
            aQ1 += ph*(hx*hy);
            aQ2 += ph*(hx*hz);
            aQ3 += ph*(hy*hy - (1.0f/3.0f));
            aQ4 += ph*(hy*hz);
            aQ5 += ph*(hz*hz - (1.0f/3.0f));
            aM0 += ph*dx; aM1 += ph*dy; aM2 += ph*dz;
            const float pu = ph*uj;
            a_nb += pu;
            aW0 += pu*dx; aW1 += pu*dy; aW2 += pu*dz;
        };
        #pragma unroll
        for (int q = 0; q < 2; ++q) {
            const float4 ph4 = phR[q], hx4 = hxR[q], hy4 = hyR[q], hz4 = hzR[q];
            const float4 dx4 = dxR[q], dy4 = dyR[q], dz4 = dzR[q], uj4 = ujR[q];
            acc(ph4.x, hx4.x, hy4.x, hz4.x, dx4.x, dy4.x, dz4.x, uj4.x);
            acc(ph4.y, hx4.y, hy4.y, hz4.y, dx4.y, dy4.y, dz4.y, uj4.y);
            acc(ph4.z, hx4.z, hy4.z, hz4.z, dx4.z, dy4.z, dz4.z, uj4.z);
            acc(ph4.w, hx4.w, hy4.w, hz4.w, dx4.w, dy4.w, dz4.w, uj4.w);
        }
        a_dr = red_k4(a_dr);
        aP0 = red_k4(aP0); aP1 = red_k4(aP1); aP2 = red_k4(aP2);
        aQ0 = red_k4(aQ0); aQ1 = red_k4(aQ1); aQ2 = red_k4(aQ2);
        aQ3 = red_k4(aQ3); aQ4 = red_k4(aQ4); aQ5 = red_k4(aQ5);
        aM0 = red_k4(aM0); aM1 = red_k4(aM1); aM2 = red_k4(aM2);
        a_nb = red_k4(a_nb);
        aW0 = red_k4(aW0); aW1 = red_k4(aW1); aW2 = red_k4(aW2);

        if (k4 == 0) {
            // stores (padded float4 rows -> single ds_write_b128 each)
            ((float4*)L.P4)[n]      = make_float4(aP0, aP1, aP2, 0.0f);
            ((float4*)L.Q8)[2*n]    = make_float4(aQ0, aQ1, aQ2, aQ3);
            ((float4*)L.Q8)[2*n+1]  = make_float4(aQ4, aQ5, 0.0f, 0.0f);
            ((float4*)L.M4)[n]      = make_float4(aM0, aM1, aM2, 0.0f);
            // mQ[n] = Q[n] . m_i
            const float mq0 = aQ0*mix + aQ1*miy + aQ2*miz;
            const float mq1 = aQ1*mix + aQ3*miy + aQ4*miz;
            const float mq2 = aQ2*mix + aQ4*miy + aQ5*miz;
            ((float4*)L.mQ4)[n]     = make_float4(mq0, mq1, mq2, 0.0f);
            // wv[n] = m_i x M[n]
            ((float4*)L.wv4)[n]     = make_float4(miy*aM2 - miz*aM1,
                                                  miz*aM0 - mix*aM2,
                                                  mix*aM1 - miy*aM0, 0.0f);
            // folded per-n descriptors (former phase 4a): all inputs in registers
            const float diso = mix*aM0 + miy*aM1 + miz*aM2;
            const float dsia = aQ0*mix*mix + aQ3*miy*miy + aQ5*miz*miz
                             + 2.0f*(aQ1*mix*miy + aQ2*mix*miz + aQ4*miy*miz);
            const float dnex = mix*aW0 + miy*aW1 + miz*aW2;
            p += a_dr * ws[n] + a_nb * wm[227 + n]
               + diso * wm[3 + n]  + dsia * wm[11 + n]  + dnex * wm[235 + n]
               + u_i * (diso * wm[147 + n] + dsia * wm[155 + n] + dnex * wm[243 + n]);
        }
        if (s == 8) {                   // d_amp
            const float u2 = u_i * u_i;
            p += u_i * wm[0] + u2 * wm[1] + u2 * u_i * wm[2];
        }
        if (s < EMBEDD)                 // embedding term
            p += semb[spi * EMBEDD + s] * ws[332 + s];
    }
    lds_fence();   // epilogue stores -> phase-3a / 4b reads

    // ---- phase 3a+3b fused: DMI contribution without materializing d_dmi ----
    // p_dmi = sum_a sum_m t_a[m] * B_a[m],  B_a[m] = sum_n phi_a[n]*(cw1T[m][n] + u*cw2T[m][n])
    {
        float B[8];
        #pragma unroll
        for (int m = 0; m < 8; ++m) {
            float a1 = 0.0f, a2 = 0.0f;
            #pragma unroll
            for (int n = 0; n < 8; ++n) {
                a1 = fmaf(phi[n], ws[400 + m*8 + n], a1);
                a2 = fmaf(phi[n], ws[464 + m*8 + n], a2);
            }
            B[m] = a1 + u_i * a2;
        }
        float cdmi = 0.0f;
        #pragma unroll
        for (int m = 0; m < 8; ++m) {
            const float4 wvm = ((const float4*)L.wv4)[m];   // m_i x M[m]
            const float vx = phi[m] * rx;
            const float vy = phi[m] * ry;
            const float vz = phi[m] * rz;
            const float Sx = prefix32(vx) - vx;   // exclusive suffix over edges (b > ea)
            const float Sy = prefix32(vy) - vy;
            const float Sz = prefix32(vz) - vz;
            const float cx = ry*Sz - rz*Sy;       // r_a x S
            const float cy = rz*Sx - rx*Sz;
            const float cz = rx*Sy - ry*Sx;
            cdmi = fmaf(B[m], cx*wvm.x + cy*wvm.y + cz*wvm.z, cdmi);
        }
        p += cdmi;
    }

    // ---- phase 4b: d_sae (64) + PP/QQ upper triangles (36 each), padded b128 reads ----
    {
        #pragma unroll
        for (int t2 = 0; t2 < 2; ++t2) {
            const int idx = s + t2*32;
            const int m4 = idx >> 3, n4 = idx & 7;
            const float4 mQm = ((const float4*)L.mQ4)[m4];
            const float4 Mn  = ((const float4*)L.M4)[n4];
            p += (mQm.x*Mn.x + mQm.y*Mn.y + mQm.z*Mn.z) * wm[19 + idx];
        }
        #pragma unroll
        for (int t2 = 0; t2 < 2; ++t2) {
            const int idx = s + t2*32;
            if (idx < 36) {
                const int a = TUN[idx], b = TUM[idx];
                const float4 Pa = ((const float4*)L.P4)[a];
                const float4 Pb = ((const float4*)L.P4)[b];
                const float pp = Pa.x*Pb.x + Pa.y*Pb.y + Pa.z*Pb.z;
                const float4 Qa0 = ((const float4*)L.Q8)[2*a], Qa1 = ((const float4*)L.Q8)[2*a+1];
                const float4 Qb0 = ((const float4*)L.Q8)[2*b], Qb1 = ((const float4*)L.Q8)[2*b+1];
                const float qq = Qa0.x*Qb0.x + Qa0.w*Qb0.w + Qa1.y*Qb1.y
                       + 2.0f*(Qa0.y*Qb0.y + Qa0.z*Qb0.z + Qa1.x*Qb1.x);
                p += pp * ws[8 + idx] + qq * ws[44 + idx];
            }
        }
    }

    // ---- final: reduce p within each 32-half, lane 0 writes ----
    p = red32(p);
    if (s == 0 && valid)
        out[i] = p + ws[331] + aes[spi];
}

extern "C" void kernel_launch(void* const* d_in, const int* in_sizes, int n_in,
                              void* d_out, int out_size, void* d_ws, size_t ws_size,
                              hipStream_t stream) {
    const float* pos     = (const float*)d_in[0];
    const int*   spc     = (const int*)  d_in[1];
    const float* mg      = (const float*)d_in[2];
    const int*   eidx    = (const int*)  d_in[3];
    const float* shf     = (const float*)d_in[4];
    const float* rb      = (const float*)d_in[5];
    const float* semb    = (const float*)d_in[6];
    const float* sshift  = (const float*)d_in[7];
    const float* sscale  = (const float*)d_in[8];
    const float* mshift  = (const float*)d_in[9];
    const float* mscale  = (const float*)d_in[10];
    const float* aes     = (const float*)d_in[11];
    const float* wstruct = (const float*)d_in[12];
    const float* bstruct = (const float*)d_in[13];
    const float* wmag    = (const float*)d_in[14];
    const float* bmag    = (const float*)d_in[15];
    float* out = (float*)d_out;
    float* ws  = (float*)d_ws;

    const int N = in_sizes[1];
    const int E = in_sizes[3] / 2;
    const int K = E / N;

    hipLaunchKernelGGL(magpot_setup, dim3(1), dim3(256), 0, stream,
                       sshift, sscale, mshift, mscale, wstruct, bstruct, wmag, bmag, ws);
    hipLaunchKernelGGL(magpot_main, dim3((N + 7) / 8), dim3(256), 0, stream,
                       pos, spc, mg, eidx, shf, rb, semb, aes, ws, out, N, E, K);
}